// Round 1
// baseline (238.427 us; speedup 1.0000x reference)
//
#include <hip/hip_runtime.h>
#include <hip/hip_bf16.h>
#include <math.h>

// Problem dims (fixed by reference)
#define D0n 8
#define D1n 12
#define D2n 6
#define Ln 2000
#define An 21
#define KPn 8
#define Un 48
#define PPn (Ln - KPn + 1)    // 1993 output positions
#define KKn (KPn * An)        // 168 contraction length
#define Bn (D0n * D1n * D2n)  // 576 batch rows
#define Gn (D0n * D1n)        // 96 S-groups
#define S_SIZE (Gn * Un)      // 4608
#define R_SIZE (KKn * Un)     // 8064
#define PTn 512               // positions per block
#define NTILEn 4              // ceil(1993/512)

// Monotone float<->uint encoding so unsigned atomicMax == float max
__device__ __forceinline__ unsigned int fkey(float f) {
    unsigned int u = __float_as_uint(f);
    return (u & 0x80000000u) ? ~u : (u | 0x80000000u);
}
__device__ __forceinline__ float funkey(unsigned int k) {
    return __uint_as_float((k & 0x80000000u) ? (k ^ 0x80000000u) : ~k);
}

// Kernel 1: R = log(max(softmax(P_logit, axis=A) / Q, eps)).  384 independent
// 21-wide softmaxes; one thread per (kp, u) pair, coalesced across u.
__global__ void k_profile(const float* __restrict__ P_logit,
                          const float* __restrict__ Q,
                          float* __restrict__ Rout) {
    int t = blockIdx.x * blockDim.x + threadIdx.x;
    if (t >= KPn * Un) return;
    int kp = t / Un, u = t % Un;
    const float* pl = P_logit + kp * (An * Un) + u;
    float v[An];
    float m = -INFINITY;
#pragma unroll
    for (int a = 0; a < An; ++a) { v[a] = pl[a * Un]; m = fmaxf(m, v[a]); }
    float s = 0.f;
#pragma unroll
    for (int a = 0; a < An; ++a) { v[a] = expf(v[a] - m); s += v[a]; }
    float inv = 1.f / s;
#pragma unroll
    for (int a = 0; a < An; ++a) {
        float P = v[a] * inv;
        float r = logf(fmaxf(P / Q[a], 1e-6f));
        Rout[(kp * An + a) * Un + u] = r;
    }
}

// Kernel 2: Z[b,p,u] = sum_{kk<168} X[(b*2000+p)*21 + kk] * R[kk,u]
// Block: 512 positions x all 48 u for one b.  Thread: 8 p x 12 u register tile.
// Also produces per-(d0,d1,u) max via monotone-uint atomicMax.
__global__ __launch_bounds__(256) void k_conv(const float* __restrict__ X,
                                              const float* __restrict__ R,
                                              float* __restrict__ Z,
                                              unsigned int* __restrict__ Skey) {
    __shared__ float Rs[KKn * Un];               // 32.2 KB
    __shared__ float Xs[(PTn + KPn - 1) * An];   // 43.6 KB (reused for reduce)
    const int b = blockIdx.y;
    const int p0 = blockIdx.x * PTn;
    const int t = threadIdx.x;

    for (int i = t; i < KKn * Un; i += 256) Rs[i] = R[i];
    const int nrow = min(PTn + KPn - 1, Ln - p0);
    const int nload = nrow * An;
    const float* Xb = X + ((size_t)b * Ln + p0) * An;
    for (int i = t; i < nload; i += 256) Xs[i] = Xb[i];
    __syncthreads();

    const int ug = t & 3;      // 4 u-groups of 12
    const int u0 = ug * 12;
    const int slot = t >> 2;   // 64 position slots
    const int pl0 = slot * 8;  // 8 positions per thread

    float acc[8][12];
#pragma unroll
    for (int j = 0; j < 8; ++j)
#pragma unroll
        for (int i = 0; i < 12; ++i) acc[j][i] = 0.f;

#pragma unroll 4
    for (int kk = 0; kk < KKn; ++kk) {
        const float* rp = &Rs[kk * Un + u0];
        float4 r0 = *(const float4*)(rp);
        float4 r1 = *(const float4*)(rp + 4);
        float4 r2 = *(const float4*)(rp + 8);
        float rv[12] = {r0.x, r0.y, r0.z, r0.w, r1.x, r1.y, r1.z, r1.w,
                        r2.x, r2.y, r2.z, r2.w};
        const float* xp = &Xs[pl0 * An + kk];
#pragma unroll
        for (int j = 0; j < 8; ++j) {
            float xv = xp[j * An];
#pragma unroll
            for (int i = 0; i < 12; ++i)
                acc[j][i] = fmaf(xv, rv[i], acc[j][i]);
        }
    }

    float tmax[12];
#pragma unroll
    for (int i = 0; i < 12; ++i) tmax[i] = -INFINITY;

#pragma unroll
    for (int j = 0; j < 8; ++j) {
        int p = p0 + pl0 + j;
        if (p < PPn) {
            float* zp = Z + ((size_t)b * PPn + p) * Un + u0;
            float4 z0 = {acc[j][0], acc[j][1], acc[j][2], acc[j][3]};
            float4 z1 = {acc[j][4], acc[j][5], acc[j][6], acc[j][7]};
            float4 z2 = {acc[j][8], acc[j][9], acc[j][10], acc[j][11]};
            *(float4*)(zp) = z0;
            *(float4*)(zp + 4) = z1;
            *(float4*)(zp + 8) = z2;
#pragma unroll
            for (int i = 0; i < 12; ++i) tmax[i] = fmaxf(tmax[i], acc[j][i]);
        }
    }

    // Block-level max reduction: red[u][slot], overlaid on Xs (done reading it)
    __syncthreads();
    float* red = Xs;  // 48*64 = 3072 floats << Xs size
#pragma unroll
    for (int i = 0; i < 12; ++i) red[(u0 + i) * 64 + slot] = tmax[i];
    __syncthreads();
    if (t < Un) {
        float m = -INFINITY;
        for (int s = 0; s < 64; ++s) m = fmaxf(m, red[t * 64 + s]);
        atomicMax(&Skey[(b / D2n) * Un + t], fkey(m));
    }
}

// Kernel 3: decode monotone keys -> float S, in place.
__global__ void k_decode(unsigned int* __restrict__ Skey) {
    int t = blockIdx.x * blockDim.x + threadIdx.x;
    if (t < S_SIZE) {
        float f = funkey(Skey[t]);
        ((float*)Skey)[t] = f;
    }
}

extern "C" void kernel_launch(void* const* d_in, const int* in_sizes, int n_in,
                              void* d_out, int out_size, void* d_ws, size_t ws_size,
                              hipStream_t stream) {
    const float* X = (const float*)d_in[0];
    const float* P_logit = (const float*)d_in[1];
    const float* Q = (const float*)d_in[2];

    float* S = (float*)d_out;
    float* Rout = S + S_SIZE;
    float* Z = Rout + R_SIZE;

    // Zero the S-key region (key 0 == identity for max); capturable.
    hipMemsetAsync(d_out, 0, S_SIZE * sizeof(float), stream);

    k_profile<<<6, 64, 0, stream>>>(P_logit, Q, Rout);

    dim3 grid(NTILEn, Bn);
    k_conv<<<grid, 256, 0, stream>>>(X, Rout, Z, (unsigned int*)d_out);

    k_decode<<<(S_SIZE + 255) / 256, 256, 0, stream>>>((unsigned int*)d_out);
}

// Round 2
// 124.418 us; speedup vs baseline: 1.9163x; 1.9163x over previous
//
#include <hip/hip_runtime.h>
#include <math.h>

typedef __attribute__((ext_vector_type(8))) short short8;  // 8 bf16 = 4 VGPRs
typedef __attribute__((ext_vector_type(4))) float f32x4;

// Problem dims
#define D0n 8
#define D1n 12
#define D2n 6
#define Ln 2000
#define An 21
#define KPn 8
#define Un 48
#define PPn 1993              // L - k + 1
#define Bn 576                // D0*D1*D2
#define Gn 96                 // D0*D1
#define S_SIZE 4608
#define R_SIZE 8064

// Conv tiling
#define BPn 256               // positions per block
#define NPT 8                 // ceil(1993/256)
#define XROWS 264             // BPn + 8 (halo), padded
#define RROWS 384             // 8 q-chunks * 48 u
#define XS_BYTES (XROWS * 64) // 16896 (each row: 32 bf16 = 64B)
#define RB_BYTES (RROWS * 64) // 24576
#define RED_OFF (XS_BYTES + RB_BYTES)

// XOR swizzle: spread row-stride-64B rows across 16B bank slots.
// byte ^ (((byte>>6)&7)<<4) == byte ^ ((byte>>2)&0x70)
__device__ __forceinline__ int swz(int b) { return b ^ ((b >> 2) & 0x70); }

__device__ __forceinline__ unsigned int fkey(float f) {
    unsigned int u = __float_as_uint(f);
    return (u & 0x80000000u) ? ~u : (u | 0x80000000u);
}
__device__ __forceinline__ float funkey(unsigned int k) {
    return __uint_as_float((k & 0x80000000u) ? (k ^ 0x80000000u) : ~k);
}
__device__ __forceinline__ unsigned short f2bf(float v) {
    unsigned int b = __float_as_uint(v);
    return (unsigned short)((b + 0x7FFFu + ((b >> 16) & 1u)) >> 16);  // RNE
}

// Kernel 1: R = log(max(softmax(P_logit, A-axis)/Q, eps)); writes fp32 R to
// d_out AND bf16, alphabet-padded(21->32), pre-swizzled copy to d_ws in the
// exact layout k_conv's LDS wants: row' = q*48+u, 32 bf16 per row.
__global__ void k_profile(const float* __restrict__ P_logit,
                          const float* __restrict__ Q,
                          float* __restrict__ Rout,
                          unsigned short* __restrict__ Rb) {
    int t = blockIdx.x * blockDim.x + threadIdx.x;
    if (t >= KPn * Un) return;
    int kp = t / Un, u = t % Un;
    const float* pl = P_logit + kp * (An * Un) + u;
    float v[An];
    float m = -INFINITY;
#pragma unroll
    for (int a = 0; a < An; ++a) { v[a] = pl[a * Un]; m = fmaxf(m, v[a]); }
    float s = 0.f;
#pragma unroll
    for (int a = 0; a < An; ++a) { v[a] = expf(v[a] - m); s += v[a]; }
    float inv = 1.f / s;
    int rowp = kp * Un + u;  // row in Rb layout
#pragma unroll
    for (int a = 0; a < An; ++a) {
        float r = logf(fmaxf(v[a] * inv / Q[a], 1e-6f));
        Rout[(kp * An + a) * Un + u] = r;
        Rb[swz(rowp * 64 + a * 2) >> 1] = f2bf(r);
    }
#pragma unroll
    for (int a = An; a < 32; ++a) Rb[swz(rowp * 64 + a * 2) >> 1] = 0;
}

// Kernel 2: Z[b,p,u] = sum_q sum_a X[b, p+q, a] * R[q*21+a, u] via bf16 MFMA.
// Block: 256 positions x 48 u for one b; 8 waves, each a 32x48 output tile.
__global__ __launch_bounds__(512) void k_conv(const float* __restrict__ X,
                                              const unsigned short* __restrict__ Rb,
                                              float* __restrict__ Z,
                                              unsigned int* __restrict__ Skey) {
    __shared__ char smem[XS_BYTES + RB_BYTES + 8 * Un * 4];
    const int b = blockIdx.y;
    const int p0 = blockIdx.x * BPn;
    const int t = threadIdx.x;

    // Stage R verbatim (already bf16 + padded + swizzled in ws)
    {
        const uint4* src = (const uint4*)Rb;
        uint4* dst = (uint4*)(smem + XS_BYTES);
        for (int i = t; i < RB_BYTES / 16; i += 512) dst[i] = src[i];
    }
    // Stage X rows p0 .. p0+262 as bf16, padded to 32/row, swizzled
    {
        const int rows_avail = min(XROWS, Ln - p0);
        const int flat_avail = rows_avail * An;
        const float* Xb = X + ((size_t)b * Ln + p0) * An;
        for (int f = t; f < XROWS * An; f += 512) {
            int row = f / An, a = f - row * An;
            float v = (f < flat_avail) ? Xb[f] : 0.f;
            *(unsigned short*)(smem + swz(row * 64 + a * 2)) = f2bf(v);
        }
        for (int f = t; f < XROWS * (32 - An); f += 512) {
            int row = f / (32 - An), a = An + (f - row * (32 - An));
            *(unsigned short*)(smem + swz(row * 64 + a * 2)) = 0;
        }
    }
    __syncthreads();

    const int w = t >> 6;        // wave 0..7
    const int l = t & 63;
    const int lr = l & 15;       // fragment row/col lane index
    const int ls = l >> 4;       // k-subchunk / C-row group
    const int pw = w * 32;       // wave's position base within block

    f32x4 acc[2][3];
#pragma unroll
    for (int m = 0; m < 2; ++m)
#pragma unroll
        for (int n = 0; n < 3; ++n) acc[m][n] = (f32x4){0.f, 0.f, 0.f, 0.f};

#pragma unroll
    for (int q = 0; q < KPn; ++q) {
        const int ar = pw + q + lr;
        short8 a0 = *(const short8*)(smem + swz(ar * 64 + ls * 16));
        short8 a1 = *(const short8*)(smem + swz((ar + 16) * 64 + ls * 16));
        const int br = q * Un + lr;
        short8 b0 = *(const short8*)(smem + XS_BYTES + swz(br * 64 + ls * 16));
        short8 b1 = *(const short8*)(smem + XS_BYTES + swz((br + 16) * 64 + ls * 16));
        short8 b2 = *(const short8*)(smem + XS_BYTES + swz((br + 32) * 64 + ls * 16));
        acc[0][0] = __builtin_amdgcn_mfma_f32_16x16x32_bf16(a0, b0, acc[0][0], 0, 0, 0);
        acc[0][1] = __builtin_amdgcn_mfma_f32_16x16x32_bf16(a0, b1, acc[0][1], 0, 0, 0);
        acc[0][2] = __builtin_amdgcn_mfma_f32_16x16x32_bf16(a0, b2, acc[0][2], 0, 0, 0);
        acc[1][0] = __builtin_amdgcn_mfma_f32_16x16x32_bf16(a1, b0, acc[1][0], 0, 0, 0);
        acc[1][1] = __builtin_amdgcn_mfma_f32_16x16x32_bf16(a1, b1, acc[1][1], 0, 0, 0);
        acc[1][2] = __builtin_amdgcn_mfma_f32_16x16x32_bf16(a1, b2, acc[1][2], 0, 0, 0);
    }

    // Store Z + per-lane max (mask p >= PPn). C layout: col=lane&15,
    // row=(lane>>4)*4+reg  [m89-verified]
    float tmax[3] = {-INFINITY, -INFINITY, -INFINITY};
#pragma unroll
    for (int m = 0; m < 2; ++m) {
#pragma unroll
        for (int r = 0; r < 4; ++r) {
            int p = p0 + pw + m * 16 + ls * 4 + r;
            if (p < PPn) {
                float* zp = Z + ((size_t)b * PPn + p) * Un + lr;
#pragma unroll
                for (int n = 0; n < 3; ++n) {
                    float val = acc[m][n][r];
                    zp[n * 16] = val;
                    tmax[n] = fmaxf(tmax[n], val);
                }
            }
        }
    }

    // Reduce over the 4 ls-groups (same column), then across waves via LDS
#pragma unroll
    for (int n = 0; n < 3; ++n) {
        tmax[n] = fmaxf(tmax[n], __shfl_xor(tmax[n], 16));
        tmax[n] = fmaxf(tmax[n], __shfl_xor(tmax[n], 32));
    }
    float* red = (float*)(smem + RED_OFF);
    if (ls == 0) {
#pragma unroll
        for (int n = 0; n < 3; ++n) red[w * Un + n * 16 + lr] = tmax[n];
    }
    __syncthreads();
    if (t < Un) {
        float m = -INFINITY;
#pragma unroll
        for (int wv = 0; wv < 8; ++wv) m = fmaxf(m, red[wv * Un + t]);
        atomicMax(&Skey[(b / D2n) * Un + t], fkey(m));
    }
}

// Kernel 3: decode monotone keys -> float S, in place.
__global__ void k_decode(unsigned int* __restrict__ Skey) {
    int t = blockIdx.x * blockDim.x + threadIdx.x;
    if (t < S_SIZE) {
        float f = funkey(Skey[t]);
        ((float*)Skey)[t] = f;
    }
}

extern "C" void kernel_launch(void* const* d_in, const int* in_sizes, int n_in,
                              void* d_out, int out_size, void* d_ws, size_t ws_size,
                              hipStream_t stream) {
    const float* X = (const float*)d_in[0];
    const float* P_logit = (const float*)d_in[1];
    const float* Q = (const float*)d_in[2];

    float* S = (float*)d_out;
    float* Rout = S + S_SIZE;
    float* Z = Rout + R_SIZE;
    unsigned short* Rb = (unsigned short*)d_ws;  // 24576 bytes

    hipMemsetAsync(d_out, 0, S_SIZE * sizeof(float), stream);

    k_profile<<<6, 64, 0, stream>>>(P_logit, Q, Rout, Rb);

    dim3 grid(NPT, Bn);
    k_conv<<<grid, 512, 0, stream>>>(X, Rb, Z, (unsigned int*)d_out);

    k_decode<<<(S_SIZE + 255) / 256, 256, 0, stream>>>((unsigned int*)d_out);
}

// Round 3
// 101.776 us; speedup vs baseline: 2.3427x; 1.2225x over previous
//
#include <hip/hip_runtime.h>
#include <math.h>

typedef __attribute__((ext_vector_type(8))) short short8;  // 8 bf16 = 4 VGPRs
typedef __attribute__((ext_vector_type(4))) float f32x4;

// Problem dims
#define D0n 8
#define D1n 12
#define D2n 6
#define Ln 2000
#define An 21
#define KPn 8
#define Un 48
#define PPn 1993              // L - k + 1
#define Bn 576                // D0*D1*D2
#define Gn 96                 // D0*D1
#define S_SIZE 4608
#define R_SIZE 8064

// Conv tiling
#define BPn 256               // positions per block
#define NPT 8                 // ceil(1993/256)
#define XROWS 264             // BPn + 8 (halo)
#define XS_BYTES (XROWS * 64) // 16896 (row: 32 bf16 = 64B, 21 data + 11 zero)
#define RB_BYTES (384 * 64)   // 24576 (8 q-chunks * 48 u rows)
#define RED_OFF (XS_BYTES + RB_BYTES)

// XOR swizzle (bijective: triangular GF(2) map on bits 4-6 ^= bits 6-8 within
// each 512B / 8-row group). Writer and reader both apply swz to the address.
__device__ __forceinline__ int swz(int b) { return b ^ ((b >> 2) & 0x70); }

__device__ __forceinline__ unsigned int fkey(float f) {
    unsigned int u = __float_as_uint(f);
    return (u & 0x80000000u) ? ~u : (u | 0x80000000u);
}
__device__ __forceinline__ float funkey(unsigned int k) {
    return __uint_as_float((k & 0x80000000u) ? (k ^ 0x80000000u) : ~k);
}
__device__ __forceinline__ unsigned short f2bf(float v) {
    unsigned int b = __float_as_uint(v);
    return (unsigned short)((b + 0x7FFFu + ((b >> 16) & 1u)) >> 16);  // RNE
}

#define GLOAD_LDS16(g, l)                                                     \
    __builtin_amdgcn_global_load_lds(                                          \
        (const __attribute__((address_space(1))) void*)(g),                    \
        (__attribute__((address_space(3))) void*)(l), 16, 0, 0)

// Kernel 1: zeros the S-key region (replaces hipMemsetAsync) and computes
// R = log(max(softmax(P_logit, A-axis)/Q, eps)); fp32 R to d_out, bf16
// padded(21->32) pre-swizzled copy to ws (layout k_conv's LDS wants).
__global__ void k_profile(const float* __restrict__ P_logit,
                          const float* __restrict__ Q,
                          float* __restrict__ Rout,
                          unsigned short* __restrict__ Rb,
                          unsigned int* __restrict__ Skey) {
    int t = blockIdx.x * blockDim.x + threadIdx.x;
    if (t < S_SIZE) Skey[t] = 0u;  // key 0 == identity for monotone-uint max
    if (t >= KPn * Un) return;
    int kp = t / Un, u = t % Un;
    const float* pl = P_logit + kp * (An * Un) + u;
    float v[An];
    float m = -INFINITY;
#pragma unroll
    for (int a = 0; a < An; ++a) { v[a] = pl[a * Un]; m = fmaxf(m, v[a]); }
    float s = 0.f;
#pragma unroll
    for (int a = 0; a < An; ++a) { v[a] = expf(v[a] - m); s += v[a]; }
    float inv = 1.f / s;
    int rowp = kp * Un + u;  // row in Rb layout
#pragma unroll
    for (int a = 0; a < An; ++a) {
        float r = logf(fmaxf(v[a] * inv / Q[a], 1e-6f));
        Rout[(kp * An + a) * Un + u] = r;
        Rb[swz(rowp * 64 + a * 2) >> 1] = f2bf(r);
    }
#pragma unroll
    for (int a = An; a < 32; ++a) Rb[swz(rowp * 64 + a * 2) >> 1] = 0;
}

// Kernel 2: Z[b,p,u] = sum_q sum_a X[b,p+q,a] * R[q*21+a,u] via bf16 MFMA.
// Block: 256 positions x 48 u for one b; 8 waves, each a 32x48 output tile.
__global__ __launch_bounds__(512) void k_conv(const float* __restrict__ X,
                                              const unsigned short* __restrict__ Rb,
                                              float* __restrict__ Z,
                                              unsigned int* __restrict__ Skey) {
    __shared__ char smem[XS_BYTES + RB_BYTES + 8 * Un * 4];
    const int b = blockIdx.y;
    const int p0 = blockIdx.x * BPn;
    const int t = threadIdx.x;

    // Stage R via global_load_lds: ws copy is already bf16+padded+swizzled,
    // and the copy is linear -> wave-uniform base + lane*16 holds.
    {
        const uint4* src = (const uint4*)Rb;
        uint4* dst = (uint4*)(smem + XS_BYTES);
#pragma unroll
        for (int i = 0; i < RB_BYTES / 16 / 512; ++i) {  // 3 iters
            int idx = t + i * 512;
            GLOAD_LDS16(src + idx, dst + idx);
        }
    }
    // Zero-fill the whole X slab with b128, then overwrite valid elems only.
    {
        uint4 z4 = {0u, 0u, 0u, 0u};
        uint4* xs = (uint4*)smem;
        for (int i = t; i < XS_BYTES / 16; i += 512) xs[i] = z4;
    }
    __syncthreads();  // zero-fill visible before pair-writes (cross-thread)
    {
        const int rows_avail = min(XROWS, Ln - p0);
        const int npair = rows_avail * 11;  // 11 bf16-pairs per row (a=0..20)
        const float* Xb = X + ((size_t)b * Ln + p0) * An;
        for (int j = t; j < npair; j += 512) {
            int row = j / 11, jj = j - row * 11;
            int a = jj * 2;
            float v0 = Xb[row * An + a];
            float v1 = (a + 1 < An) ? Xb[row * An + a + 1] : 0.f;
            unsigned int pk = (unsigned int)f2bf(v0) |
                              ((unsigned int)f2bf(v1) << 16);
            *(unsigned int*)(smem + swz(row * 64 + a * 2)) = pk;
        }
    }
    __syncthreads();

    const int w = t >> 6;        // wave 0..7
    const int l = t & 63;
    const int lr = l & 15;       // fragment col lane index (u / k-row)
    const int ls = l >> 4;       // k-subchunk / C-row group
    const int pw = w * 32;       // wave's position base within block

    f32x4 acc[2][3];
#pragma unroll
    for (int m = 0; m < 2; ++m)
#pragma unroll
        for (int n = 0; n < 3; ++n) acc[m][n] = (f32x4){0.f, 0.f, 0.f, 0.f};

#pragma unroll
    for (int q = 0; q < KPn; ++q) {
        const int ar = pw + q + lr;
        short8 a0 = *(const short8*)(smem + swz(ar * 64 + ls * 16));
        short8 a1 = *(const short8*)(smem + swz((ar + 16) * 64 + ls * 16));
        const int br = q * Un + lr;
        short8 b0 = *(const short8*)(smem + XS_BYTES + swz(br * 64 + ls * 16));
        short8 b1 = *(const short8*)(smem + XS_BYTES + swz((br + 16) * 64 + ls * 16));
        short8 b2 = *(const short8*)(smem + XS_BYTES + swz((br + 32) * 64 + ls * 16));
        acc[0][0] = __builtin_amdgcn_mfma_f32_16x16x32_bf16(a0, b0, acc[0][0], 0, 0, 0);
        acc[0][1] = __builtin_amdgcn_mfma_f32_16x16x32_bf16(a0, b1, acc[0][1], 0, 0, 0);
        acc[0][2] = __builtin_amdgcn_mfma_f32_16x16x32_bf16(a0, b2, acc[0][2], 0, 0, 0);
        acc[1][0] = __builtin_amdgcn_mfma_f32_16x16x32_bf16(a1, b0, acc[1][0], 0, 0, 0);
        acc[1][1] = __builtin_amdgcn_mfma_f32_16x16x32_bf16(a1, b1, acc[1][1], 0, 0, 0);
        acc[1][2] = __builtin_amdgcn_mfma_f32_16x16x32_bf16(a1, b2, acc[1][2], 0, 0, 0);
    }

    // Store Z + per-lane max. C layout: col=lane&15, row=(lane>>4)*4+reg.
    float tmax[3] = {-INFINITY, -INFINITY, -INFINITY};
#pragma unroll
    for (int m = 0; m < 2; ++m) {
#pragma unroll
        for (int r = 0; r < 4; ++r) {
            int p = p0 + pw + m * 16 + ls * 4 + r;
            if (p < PPn) {
                float* zp = Z + ((size_t)b * PPn + p) * Un + lr;
#pragma unroll
                for (int n = 0; n < 3; ++n) {
                    float val = acc[m][n][r];
                    zp[n * 16] = val;
                    tmax[n] = fmaxf(tmax[n], val);
                }
            }
        }
    }

    // Column max: reduce over ls-groups (xor 16, 32), then across waves.
#pragma unroll
    for (int n = 0; n < 3; ++n) {
        tmax[n] = fmaxf(tmax[n], __shfl_xor(tmax[n], 16));
        tmax[n] = fmaxf(tmax[n], __shfl_xor(tmax[n], 32));
    }
    float* red = (float*)(smem + RED_OFF);
    if (ls == 0) {
#pragma unroll
        for (int n = 0; n < 3; ++n) red[w * Un + n * 16 + lr] = tmax[n];
    }
    __syncthreads();
    if (t < Un) {
        float m = -INFINITY;
#pragma unroll
        for (int wv = 0; wv < 8; ++wv) m = fmaxf(m, red[wv * Un + t]);
        atomicMax(&Skey[(b / D2n) * Un + t], fkey(m));
    }
}

// Kernel 3: decode monotone keys -> float S, in place.
__global__ void k_decode(unsigned int* __restrict__ Skey) {
    int t = blockIdx.x * blockDim.x + threadIdx.x;
    if (t < S_SIZE) {
        float f = funkey(Skey[t]);
        ((float*)Skey)[t] = f;
    }
}

extern "C" void kernel_launch(void* const* d_in, const int* in_sizes, int n_in,
                              void* d_out, int out_size, void* d_ws, size_t ws_size,
                              hipStream_t stream) {
    const float* X = (const float*)d_in[0];
    const float* P_logit = (const float*)d_in[1];
    const float* Q = (const float*)d_in[2];

    float* S = (float*)d_out;
    float* Rout = S + S_SIZE;
    float* Z = Rout + R_SIZE;
    unsigned short* Rb = (unsigned short*)d_ws;  // 24576 bytes of ws

    // k_profile zeros the S-key region (no hipMemsetAsync node in the graph).
    k_profile<<<(S_SIZE + 63) / 64, 64, 0, stream>>>(P_logit, Q, Rout, Rb,
                                                     (unsigned int*)d_out);

    dim3 grid(NPT, Bn);
    k_conv<<<grid, 512, 0, stream>>>(X, Rb, Z, (unsigned int*)d_out);

    k_decode<<<(S_SIZE + 255) / 256, 256, 0, stream>>>((unsigned int*)d_out);
}